// Round 21
// baseline (455.700 us; speedup 1.0000x reference)
//
#include <hip/hip_runtime.h>

#define SCALE_LORA 2.0f
// r21: i8 GEMM at 256x128 tile (wave 64x64, acc=64 VGPR) -> fits the
// (512,4) register cap => TRUE 2 blocks/CU (r18's idea minus its spill:
// acc footprint halved). Skeleton = r18's mid-tile-rendezvous (race-free,
// i8-verified). NBUF=2, 48 KiB LDS/block. Preproc = r20 (fused).
#define BM 256
#define BN 128
#define BKI 64

#define AS1 __attribute__((address_space(1)))
#define AS3 __attribute__((address_space(3)))

using f32x4  = __attribute__((ext_vector_type(4))) float;
using i32x4  = __attribute__((ext_vector_type(4))) int;
using i32x16 = __attribute__((ext_vector_type(16))) int;
using u16x8  = __attribute__((ext_vector_type(8))) unsigned short;

#define MFMAI8(a, b, c) __builtin_amdgcn_mfma_i32_32x32x32_i8((a), (b), (c), 0, 0, 0)

static __device__ __forceinline__ unsigned short f2bf_rne(float f) {
  unsigned int u = __builtin_bit_cast(unsigned int, f);
  u += 0x7FFFu + ((u >> 16) & 1u);
  return (unsigned short)(u >> 16);
}
static __device__ __forceinline__ float bf2f(unsigned short b) {
  unsigned int u = (unsigned int)b << 16;
  return __builtin_bit_cast(float, u);
}

// ---------- kernel 1: FUSED  quant_x (bid < M)  +  build_wt (bid >= M) ----
__global__ void fused_pre_kernel(const float* __restrict__ x,
                                 signed char* __restrict__ xq,
                                 float* __restrict__ sx,
                                 const float* __restrict__ W,
                                 const float* __restrict__ A,
                                 const float* __restrict__ Bmat,
                                 unsigned short* __restrict__ WT,
                                 int K, int N, int R, int Mrows) {
  __shared__ float wmax[4];
  __shared__ float Bs[16][64];
  __shared__ unsigned short Tt[64][66];

  int t = threadIdx.x;
  if ((int)blockIdx.x < Mrows) {
    long row = blockIdx.x;
    const float* xr = x + row * (long)K;
    f32x4 v[4];
    #pragma unroll
    for (int j = 0; j < 4; ++j)
      v[j] = *(const f32x4*)(xr + 4 * t + 1024 * j);
    float m = 0.f;
    #pragma unroll
    for (int j = 0; j < 4; ++j)
      #pragma unroll
      for (int e = 0; e < 4; ++e) m = fmaxf(m, fabsf(v[j][e]));
    #pragma unroll
    for (int off = 1; off < 64; off <<= 1)
      m = fmaxf(m, __shfl_xor(m, off));
    if ((t & 63) == 0) wmax[t >> 6] = m;
    __syncthreads();
    float rm = fmaxf(fmaxf(wmax[0], wmax[1]), fmaxf(wmax[2], wmax[3]));
    rm = fmaxf(rm, 1e-20f);
    float inv = 127.0f / rm;
    #pragma unroll
    for (int j = 0; j < 4; ++j) {
      int b0 = max(-127, min(127, (int)rintf(v[j][0] * inv)));
      int b1 = max(-127, min(127, (int)rintf(v[j][1] * inv)));
      int b2 = max(-127, min(127, (int)rintf(v[j][2] * inv)));
      int b3 = max(-127, min(127, (int)rintf(v[j][3] * inv)));
      unsigned int pk = (b0 & 255) | ((b1 & 255) << 8) | ((b2 & 255) << 16)
                        | ((unsigned)b3 << 24);
      *(unsigned int*)(xq + row * (long)K + 4 * t + 1024 * j) = pk;
    }
    if (t == 0) sx[row] = rm * (1.0f / 127.0f);
  } else {
    int tile = (int)blockIdx.x - Mrows;
    int ntn = N >> 6;
    int kt = tile / ntn, nt = tile - kt * ntn;
    int k0 = kt << 6, n0 = nt << 6;
    int tx = t & 63, ty = t >> 6;

    for (int i = t; i < R * 64; i += 256)
      Bs[i >> 6][i & 63] = Bmat[(long)(i >> 6) * N + n0 + (i & 63)];
    __syncthreads();

    for (int it = 0; it < 16; ++it) {
      int kl = (it << 2) + ty;
      long kg = k0 + kl;
      float w = W[kg * N + n0 + tx];
      const float* Ar = A + kg * R;
      float s = 0.f;
      for (int r = 0; r < R; ++r) s += Ar[r] * Bs[r][tx];
      Tt[kl][tx] = f2bf_rne(w + SCALE_LORA * s);
    }
    __syncthreads();

    for (int it = 0; it < 16; ++it) {
      int nn = (it << 2) + ty;
      WT[(long)(n0 + nn) * K + k0 + tx] = Tt[tx][nn];
    }
  }
}

// ---------- kernel 2: WT bf16 -> colmax + i8 quantize ----------
__global__ void quantize_wt_kernel(const unsigned short* __restrict__ WT,
                                   signed char* __restrict__ WTq,
                                   float* __restrict__ sw, int K) {
  __shared__ float wmax[4];
  long n = blockIdx.x;
  const unsigned short* wr = WT + n * (long)K;
  int t = threadIdx.x;
  u16x8 u0 = *(const u16x8*)(wr + 8 * t);
  u16x8 u1 = *(const u16x8*)(wr + 8 * t + 2048);
  float f0[8], f1[8];
  float m = 0.f;
  #pragma unroll
  for (int e = 0; e < 8; ++e) {
    f0[e] = bf2f(u0[e]); f1[e] = bf2f(u1[e]);
    m = fmaxf(m, fmaxf(fabsf(f0[e]), fabsf(f1[e])));
  }
  #pragma unroll
  for (int off = 1; off < 64; off <<= 1)
    m = fmaxf(m, __shfl_xor(m, off));
  if ((t & 63) == 0) wmax[t >> 6] = m;
  __syncthreads();
  float rm = fmaxf(fmaxf(wmax[0], wmax[1]), fmaxf(wmax[2], wmax[3]));
  rm = fmaxf(rm, 1e-20f);
  float inv = 127.0f / rm;
  unsigned long long p0 = 0, p1 = 0;
  #pragma unroll
  for (int e = 0; e < 8; ++e) {
    int q0 = max(-127, min(127, (int)rintf(f0[e] * inv)));
    int q1 = max(-127, min(127, (int)rintf(f1[e] * inv)));
    p0 |= (unsigned long long)(q0 & 255) << (8 * e);
    p1 |= (unsigned long long)(q1 & 255) << (8 * e);
  }
  *(unsigned long long*)(WTq + n * (long)K + 8 * t) = p0;
  *(unsigned long long*)(WTq + n * (long)K + 8 * t + 2048) = p1;
  if (t == 0) sw[n] = rm * (1.0f / 127.0f);
}

// ---------- kernel 3: i8 GEMM, 256x128 tile, NBUF=2, 2 blocks/CU ----------
// LDS per block 48 KiB: A bufs 2x16 KB at b*16384; B bufs 2x8 KB at
// 32768 + b*8192. Row r slot s holds logical granule s ^ ((r>>1)&3)
// (verified swizzle family). Skeleton: vmcnt(3)+BAR; 8 reads; MFMA ks0;
// lgkm0+BAR rendezvous; stage t+2 (3 loads) into this buf; MFMA ks1.
__global__ __launch_bounds__(512, 4) void gemm_kernel(
    const signed char* __restrict__ Xq,   // M x K i8
    const signed char* __restrict__ WTq,  // N x K i8
    const float* __restrict__ bias,       // N f32
    const float* __restrict__ sx,         // M f32
    const float* __restrict__ sw,         // N f32
    float* __restrict__ out,              // M x N f32
    int M, int N, int K)
{
  extern __shared__ char ldsc[];   // 48 KiB

  int nwg = gridDim.x;
  int bid = blockIdx.x;
  if ((nwg & 7) == 0) {
    int cpx = nwg >> 3;
    bid = (bid & 7) * cpx + (bid >> 3);
  }
  int ntn = N / BN;                 // 32
  int tm = bid / ntn;
  int tn = bid - tm * ntn;
  const long m0 = (long)tm * BM;
  const long n0 = (long)tn * BN;

  int tid  = threadIdx.x;
  int lane = tid & 63;
  int wave = tid >> 6;
  int wr = wave >> 1;        // 0..3 : 64-row band (M)
  int wc = wave & 1;         // 0..1 : 64-col band (N)
  int l31 = lane & 31;
  int g   = lane >> 5;

  i32x16 acc[2][2] = {};     // 64 VGPR

  // staging: thread t -> row t>>2, dest slot t&3; source granule =
  // (t&3) ^ ((row>>1)&3) = (t&3) ^ ((t>>3)&3)
  int srccol = 16 * ((tid & 3) ^ ((tid >> 3) & 3));
  const signed char* aSrc = Xq + (m0 + (tid >> 2)) * (long)K + srccol;
  const signed char* bSrc = WTq + (n0 + (tid >> 2)) * (long)K + srccol;
  const int ldsByte = tid * 16;

  const int rsw = (l31 >> 1) & 3;
  const int so0 = 16 * ((0 + g) ^ rsw);   // ks=0
  const int so1 = 16 * ((2 + g) ^ rsw);   // ks=1
  const int rowA = wr * 4096 + l31 * 64;  // + fm*2048
  const int rowB = wc * 4096 + l31 * 64;  // + fn*2048

  const int nt = K / BKI;   // 64

  // A: 2 loads (rows t>>2, t>>2+128); B: 1 load (rows 0..127)
#define STAGE(buf, kt) do {                                                  \
    _Pragma("unroll")                                                        \
    for (int j_ = 0; j_ < 2; ++j_)                                           \
      __builtin_amdgcn_global_load_lds(                                      \
        (const AS1 void*)(aSrc + j_*128*(long)K + (long)(kt)*BKI),           \
        (AS3 void*)(ldsc + (buf)*16384 + j_*8192 + ldsByte), 16, 0, 0);      \
    __builtin_amdgcn_global_load_lds(                                        \
      (const AS1 void*)(bSrc + (long)(kt)*BKI),                              \
      (AS3 void*)(ldsc + 32768 + (buf)*8192 + ldsByte), 16, 0, 0);           \
  } while (0)

#define SBAR  __builtin_amdgcn_sched_barrier(0)

#define TILE(BUFI, VMSTR, STG) do {                                          \
    asm volatile("s_waitcnt vmcnt(" VMSTR ")" ::: "memory");                 \
    __builtin_amdgcn_s_barrier();                                            \
    SBAR;                                                                    \
    const char* Ab_ = ldsc + (BUFI)*16384 + rowA;                            \
    const char* Bb_ = ldsc + 32768 + (BUFI)*8192 + rowB;                     \
    i32x4 a0_[2], b0_[2], a1_[2], b1_[2];                                    \
    _Pragma("unroll")                                                        \
    for (int fm_ = 0; fm_ < 2; ++fm_)                                        \
      a0_[fm_] = *(const i32x4*)(Ab_ + fm_*2048 + so0);                      \
    _Pragma("unroll")                                                        \
    for (int fn_ = 0; fn_ < 2; ++fn_)                                        \
      b0_[fn_] = *(const i32x4*)(Bb_ + fn_*2048 + so0);                      \
    _Pragma("unroll")                                                        \
    for (int fm_ = 0; fm_ < 2; ++fm_)                                        \
      a1_[fm_] = *(const i32x4*)(Ab_ + fm_*2048 + so1);                      \
    _Pragma("unroll")                                                        \
    for (int fn_ = 0; fn_ < 2; ++fn_)                                        \
      b1_[fn_] = *(const i32x4*)(Bb_ + fn_*2048 + so1);                      \
    __builtin_amdgcn_s_setprio(1);                                           \
    _Pragma("unroll")                                                        \
    for (int fm_ = 0; fm_ < 2; ++fm_)                                        \
      _Pragma("unroll")                                                      \
      for (int fn_ = 0; fn_ < 2; ++fn_)                                      \
        acc[fm_][fn_] = MFMAI8(a0_[fm_], b0_[fn_], acc[fm_][fn_]);           \
    __builtin_amdgcn_s_setprio(0);                                           \
    asm volatile("s_waitcnt lgkmcnt(0)" ::: "memory");                       \
    SBAR;                                                                    \
    __builtin_amdgcn_s_barrier();                                            \
    STG;                                                                     \
    SBAR;                                                                    \
    __builtin_amdgcn_s_setprio(1);                                           \
    _Pragma("unroll")                                                        \
    for (int fm_ = 0; fm_ < 2; ++fm_)                                        \
      _Pragma("unroll")                                                      \
      for (int fn_ = 0; fn_ < 2; ++fn_)                                      \
        acc[fm_][fn_] = MFMAI8(a1_[fm_], b1_[fn_], acc[fm_][fn_]);           \
    __builtin_amdgcn_s_setprio(0);                                           \
    SBAR;                                                                    \
  } while (0)

  // prologue: tiles 0,1 staged (6 loads in flight)
  STAGE(0, 0);
  STAGE(1, 1);

  // steady: vmcnt(3) at tile t drains t's 3 loads (leaves t+1's 3);
  // mid-tile lgkm0+BAR certifies all reads of buf t done -> stage t+2.
  for (int i = 0; i < 31; ++i) {
    int t2 = 2 * i;
    TILE(0, "3", STAGE(0, t2 + 2));
    TILE(1, "3", STAGE(1, t2 + 3));
  }
  TILE(0, "3", {});   // tile 62 (63's loads stay in flight)
  TILE(1, "0", {});   // tile 63

#undef TILE
#undef STAGE

  // epilogue: 32x32 C/D layout: col = lane&31, row = (reg&3)+8*(reg>>2)+4*g
  #pragma unroll
  for (int fn = 0; fn < 2; ++fn) {
    long col = n0 + wc * 64 + fn * 32 + l31;
    float swc = sw[col];
    float bv = bias[col];
    #pragma unroll
    for (int fm = 0; fm < 2; ++fm) {
      long rbase = m0 + wr * 64 + fm * 32 + 4 * g;
      #pragma unroll
      for (int r = 0; r < 16; ++r) {
        long row = rbase + (r & 3) + 8 * (r >> 2);
        out[row * (long)N + col] = (float)acc[fm][fn][r] * sx[row] * swc + bv;
      }
    }
  }
}

extern "C" void kernel_launch(void* const* d_in, const int* in_sizes, int n_in,
                              void* d_out, int out_size, void* d_ws, size_t ws_size,
                              hipStream_t stream) {
  const float* x    = (const float*)d_in[0];
  const float* W    = (const float*)d_in[1];
  const float* b    = (const float*)d_in[2];
  const float* A    = (const float*)d_in[3];
  const float* Bm   = (const float*)d_in[4];

  const long D_out = in_sizes[2];                 // 4096
  const long D_in  = (long)in_sizes[1] / D_out;   // 4096
  const long M     = (long)in_sizes[0] / D_in;    // 16384
  const int  R     = (int)((long)in_sizes[3] / D_in);  // 16
  const int  K = (int)D_in, N = (int)D_out;

  char* wsc = (char*)d_ws;
  signed char*    xq  = (signed char*)wsc;
  unsigned short* wt  = (unsigned short*)(wsc + (size_t)M * K);
  signed char*    wtq = (signed char*)(wsc + (size_t)M * K + (size_t)N * K * 2);
  float* sx = (float*)(wsc + (size_t)M * K + (size_t)N * K * 3);
  float* sw = (float*)(wsc + (size_t)M * K + (size_t)N * K * 3 + (size_t)M * 4);

  int nbuild = (K >> 6) * (N >> 6);               // 4096
  fused_pre_kernel<<<(int)M + nbuild, 256, 0, stream>>>(
      x, xq, sx, W, A, Bm, wt, K, N, R, (int)M);
  quantize_wt_kernel<<<N, 256, 0, stream>>>(wt, wtq, sw, K);

  int grid = (int)((M / BM) * ((long)N / BN));    // 64 * 32 = 2048
  gemm_kernel<<<grid, 512, 48 * 1024, stream>>>(
      xq, wtq, b, sx, sw, (float*)d_out, (int)M, N, K);
}

// Round 22
// 446.840 us; speedup vs baseline: 1.0198x; 1.0198x over previous
//
#include <hip/hip_runtime.h>

#define SCALE_LORA 2.0f
// FINAL (r22 = r14 byte-exact, the measured optimum: 445.7 µs total).
// i8 GEMM: 256x256 tile, BK=128 i8, 8 waves, 32x32x32 i8 MFMA, NBUF=2,
// 4-phase schedule; preproc: coalesced quant_x + bf16 build_wt + one-pass
// quantize_wt. 21 rounds of variants (free-run, deep ring, reg prefetch,
// occupancy, fence shaping) all measured 314-334 µs GEMM => plateau.
#define BM 256
#define BN 256
#define BKI 128

#define AS1 __attribute__((address_space(1)))
#define AS3 __attribute__((address_space(3)))

using f32x4  = __attribute__((ext_vector_type(4))) float;
using i32x4  = __attribute__((ext_vector_type(4))) int;
using i32x16 = __attribute__((ext_vector_type(16))) int;
using u16x8  = __attribute__((ext_vector_type(8))) unsigned short;

#define MFMAI8(a, b, c) __builtin_amdgcn_mfma_i32_32x32x32_i8((a), (b), (c), 0, 0, 0)

static __device__ __forceinline__ unsigned short f2bf_rne(float f) {
  unsigned int u = __builtin_bit_cast(unsigned int, f);
  u += 0x7FFFu + ((u >> 16) & 1u);
  return (unsigned short)(u >> 16);
}
static __device__ __forceinline__ float bf2f(unsigned short b) {
  unsigned int u = (unsigned int)b << 16;
  return __builtin_bit_cast(float, u);
}

// ---------- kernel 1: per-row quantize x -> i8 (fully coalesced) ----------
__global__ void quant_x_kernel(const float* __restrict__ x,
                               signed char* __restrict__ xq,
                               float* __restrict__ sx, int K) {
  __shared__ float wmax[4];
  long row = blockIdx.x;
  const float* xr = x + row * (long)K;
  int t = threadIdx.x;
  f32x4 v[4];
  #pragma unroll
  for (int j = 0; j < 4; ++j)
    v[j] = *(const f32x4*)(xr + 4 * t + 1024 * j);
  float m = 0.f;
  #pragma unroll
  for (int j = 0; j < 4; ++j)
    #pragma unroll
    for (int e = 0; e < 4; ++e) m = fmaxf(m, fabsf(v[j][e]));
  #pragma unroll
  for (int off = 1; off < 64; off <<= 1)
    m = fmaxf(m, __shfl_xor(m, off));
  if ((t & 63) == 0) wmax[t >> 6] = m;
  __syncthreads();
  float rm = fmaxf(fmaxf(wmax[0], wmax[1]), fmaxf(wmax[2], wmax[3]));
  rm = fmaxf(rm, 1e-20f);
  float inv = 127.0f / rm;
  #pragma unroll
  for (int j = 0; j < 4; ++j) {
    int b0 = max(-127, min(127, (int)rintf(v[j][0] * inv)));
    int b1 = max(-127, min(127, (int)rintf(v[j][1] * inv)));
    int b2 = max(-127, min(127, (int)rintf(v[j][2] * inv)));
    int b3 = max(-127, min(127, (int)rintf(v[j][3] * inv)));
    unsigned int pk = (b0 & 255) | ((b1 & 255) << 8) | ((b2 & 255) << 16)
                      | ((unsigned)b3 << 24);
    *(unsigned int*)(xq + row * (long)K + 4 * t + 1024 * j) = pk;
  }
  if (t == 0) sx[row] = rm * (1.0f / 127.0f);
}

// ---------- kernel 2: W_eff^T = (W + 2*A@B)^T as bf16 (r7-proven) ----------
__global__ void build_wt_kernel(const float* __restrict__ W,
                                const float* __restrict__ A,
                                const float* __restrict__ Bmat,
                                unsigned short* __restrict__ WT,
                                int K, int N, int R) {
  __shared__ float Bs[16][64];
  __shared__ unsigned short Tt[64][66];
  int ntn = N >> 6;
  int kt = blockIdx.x / ntn, nt = blockIdx.x - kt * ntn;
  int k0 = kt << 6, n0 = nt << 6;
  int t = threadIdx.x;
  int tx = t & 63, ty = t >> 6;

  for (int i = t; i < R * 64; i += 256)
    Bs[i >> 6][i & 63] = Bmat[(long)(i >> 6) * N + n0 + (i & 63)];
  __syncthreads();

  for (int it = 0; it < 16; ++it) {
    int kl = (it << 2) + ty;
    long kg = k0 + kl;
    float w = W[kg * N + n0 + tx];
    const float* Ar = A + kg * R;
    float s = 0.f;
    for (int r = 0; r < R; ++r) s += Ar[r] * Bs[r][tx];
    Tt[kl][tx] = f2bf_rne(w + SCALE_LORA * s);
  }
  __syncthreads();

  for (int it = 0; it < 16; ++it) {
    int nn = (it << 2) + ty;
    WT[(long)(n0 + nn) * K + k0 + tx] = Tt[tx][nn];
  }
}

// ---------- kernel 3: WT bf16 -> colmax + i8 quantize (one pass) ----------
__global__ void quantize_wt_kernel(const unsigned short* __restrict__ WT,
                                   signed char* __restrict__ WTq,
                                   float* __restrict__ sw, int K) {
  __shared__ float wmax[4];
  long n = blockIdx.x;
  const unsigned short* wr = WT + n * (long)K;
  int t = threadIdx.x;
  u16x8 u0 = *(const u16x8*)(wr + 8 * t);
  u16x8 u1 = *(const u16x8*)(wr + 8 * t + 2048);
  float f0[8], f1[8];
  float m = 0.f;
  #pragma unroll
  for (int e = 0; e < 8; ++e) {
    f0[e] = bf2f(u0[e]); f1[e] = bf2f(u1[e]);
    m = fmaxf(m, fmaxf(fabsf(f0[e]), fabsf(f1[e])));
  }
  #pragma unroll
  for (int off = 1; off < 64; off <<= 1)
    m = fmaxf(m, __shfl_xor(m, off));
  if ((t & 63) == 0) wmax[t >> 6] = m;
  __syncthreads();
  float rm = fmaxf(fmaxf(wmax[0], wmax[1]), fmaxf(wmax[2], wmax[3]));
  rm = fmaxf(rm, 1e-20f);
  float inv = 127.0f / rm;
  unsigned long long p0 = 0, p1 = 0;
  #pragma unroll
  for (int e = 0; e < 8; ++e) {
    int q0 = max(-127, min(127, (int)rintf(f0[e] * inv)));
    int q1 = max(-127, min(127, (int)rintf(f1[e] * inv)));
    p0 |= (unsigned long long)(q0 & 255) << (8 * e);
    p1 |= (unsigned long long)(q1 & 255) << (8 * e);
  }
  *(unsigned long long*)(WTq + n * (long)K + 8 * t) = p0;
  *(unsigned long long*)(WTq + n * (long)K + 8 * t + 2048) = p1;
  if (t == 0) sw[n] = rm * (1.0f / 127.0f);
}

// ---------- kernel 4: i8 4-phase GEMM (r13/r14-passing core) ----------
__global__ __launch_bounds__(512, 2) void gemm_kernel(
    const signed char* __restrict__ Xq,   // M x K i8
    const signed char* __restrict__ WTq,  // N x K i8 (pre-transposed)
    const float* __restrict__ bias,       // N f32
    const float* __restrict__ sx,         // M f32
    const float* __restrict__ sw,         // N f32
    float* __restrict__ out,              // M x N f32
    int M, int N, int K)
{
  extern __shared__ char ldsc[];   // 128 KiB

  int nwg = gridDim.x;
  int bid = blockIdx.x;
  if ((nwg & 7) == 0) {
    int cpx = nwg >> 3;
    bid = (bid & 7) * cpx + (bid >> 3);
  }
  int ntn = N / BN;
  int tm = bid / ntn;
  int tn = bid - tm * ntn;
  const long m0 = (long)tm * BM;
  const long n0 = (long)tn * BN;

  int tid  = threadIdx.x;
  int lane = tid & 63;
  int wave = tid >> 6;
  int wr = wave >> 2;
  int wc = wave & 3;
  int l31 = lane & 31;
  int g   = lane >> 5;

  i32x16 acc[4][2] = {};

  int srcg = 16 * ((tid & 7) ^ ((tid >> 3) & 7));
  const signed char* aSrc = Xq + (m0 + (tid >> 3)) * (long)K + srcg;
  const signed char* bSrc = WTq + (n0 + (tid >> 3)) * (long)K + srcg;
  const int ldsByte = tid * 16;

  const int sw7 = l31 & 7;
  const int so0 = 16 * ((0 + g) ^ sw7);
  const int so1 = 16 * ((2 + g) ^ sw7);
  const int so2 = 16 * ((4 + g) ^ sw7);
  const int so3 = 16 * ((6 + g) ^ sw7);
  const int rowA = wr * 16384 + l31 * 128;
  const int rowB = wc * 8192  + l31 * 128;

  const int nt = K / BKI;   // 32

#define STGA(b, h, kt) do {                                                  \
    _Pragma("unroll")                                                        \
    for (int j_ = 0; j_ < 2; ++j_)                                           \
      __builtin_amdgcn_global_load_lds(                                      \
        (const AS1 void*)(aSrc + ((h)*128 + j_*64)*(long)K + (long)(kt)*BKI),\
        (AS3 void*)(ldsc + (b)*32768 + (h)*16384 + j_*8192 + ldsByte),       \
        16, 0, 0);                                                           \
  } while (0)
#define STGB(b, h, kt) do {                                                  \
    _Pragma("unroll")                                                        \
    for (int j_ = 0; j_ < 2; ++j_)                                           \
      __builtin_amdgcn_global_load_lds(                                      \
        (const AS1 void*)(bSrc + ((h)*128 + j_*64)*(long)K + (long)(kt)*BKI),\
        (AS3 void*)(ldsc + 65536 + (b)*32768 + (h)*16384 + j_*8192 +         \
                    ldsByte), 16, 0, 0);                                     \
  } while (0)

#define SBAR  __builtin_amdgcn_sched_barrier(0)
#define BAR   __builtin_amdgcn_s_barrier()
#define LGKM0 do { asm volatile("s_waitcnt lgkmcnt(0)" ::: "memory"); SBAR; } while (0)
#define LGKM8 do { asm volatile("s_waitcnt lgkmcnt(8)" ::: "memory"); } while (0)

#define RD_A(arr, fmB) do {                                                  \
    _Pragma("unroll")                                                        \
    for (int fi_ = 0; fi_ < 2; ++fi_) {                                      \
      const char* p_ = Ab_ + ((fmB) + fi_) * 4096;                           \
      arr[fi_][0] = *(const i32x4*)(p_ + so0);                               \
      arr[fi_][1] = *(const i32x4*)(p_ + so1);                               \
      arr[fi_][2] = *(const i32x4*)(p_ + so2);                               \
      arr[fi_][3] = *(const i32x4*)(p_ + so3);                               \
    }                                                                        \
  } while (0)
#define RD_B(arr, fnB) do {                                                  \
    const char* p_ = Bb_ + (fnB) * 4096;                                     \
    arr[0] = *(const i32x4*)(p_ + so0);                                      \
    arr[1] = *(const i32x4*)(p_ + so1);                                      \
    arr[2] = *(const i32x4*)(p_ + so2);                                      \
    arr[3] = *(const i32x4*)(p_ + so3);                                      \
  } while (0)
#define QUAD(aarr, barr, fmB, fn) do {                                       \
    __builtin_amdgcn_s_setprio(1);                                           \
    _Pragma("unroll")                                                        \
    for (int fi_ = 0; fi_ < 2; ++fi_)                                        \
      _Pragma("unroll")                                                      \
      for (int ks_ = 0; ks_ < 4; ++ks_)                                      \
        acc[(fmB)+fi_][fn] = MFMAI8(aarr[fi_][ks_], barr[ks_],               \
                                    acc[(fmB)+fi_][fn]);                     \
    __builtin_amdgcn_s_setprio(0);                                           \
  } while (0)

#define TILE4(B_, W1, S1, S2, S3, S4) do {                                   \
    asm volatile("s_waitcnt vmcnt(" W1 ")" ::: "memory");                    \
    BAR;                                                                     \
    const char* Ab_ = ldsc + (B_)*32768 + rowA;                              \
    const char* Bb_ = ldsc + 65536 + (B_)*32768 + rowB;                      \
    i32x4 af_[2][4], bl_[4], bh_[4], ag_[2][4];                              \
    RD_A(af_, 0);                                                            \
    RD_B(bl_, 0);                                                            \
    S1;                                                                      \
    LGKM8;                                                                   \
    SBAR; BAR; LGKM0;                                                        \
    QUAD(af_, bl_, 0, 0);                                                    \
    SBAR; BAR;                                                               \
    RD_B(bh_, 1);                                                            \
    S2;                                                                      \
    SBAR; BAR; LGKM0;                                                        \
    QUAD(af_, bh_, 0, 1);                                                    \
    SBAR; BAR;                                                               \
    RD_A(ag_, 2);                                                            \
    S3;                                                                      \
    SBAR; BAR; LGKM0;                                                        \
    QUAD(ag_, bl_, 2, 0);                                                    \
    SBAR; BAR;                                                               \
    S4;                                                                      \
    SBAR;                                                                    \
    QUAD(ag_, bh_, 2, 1);                                                    \
    SBAR;                                                                    \
  } while (0)

  STGB(0, 0, 0); STGA(0, 0, 0); STGB(0, 1, 0); STGA(0, 1, 0);
  STGB(1, 0, 1); STGA(1, 0, 1);

  const int npair = nt / 2;
  for (int i = 0; i < npair - 1; ++i) {
    int t2 = 2 * i;
    TILE4(0, "4", STGB(1,1,t2+1), STGA(1,1,t2+1), STGB(0,0,t2+2), STGA(0,0,t2+2));
    TILE4(1, "4", STGB(0,1,t2+2), STGA(0,1,t2+2), STGB(1,0,t2+3), STGA(1,0,t2+3));
  }
  TILE4(0, "4", STGB(1,1,nt-1), STGA(1,1,nt-1), , );
  TILE4(1, "0", , , , );

#undef TILE4
#undef QUAD
#undef RD_A
#undef RD_B
#undef STGA
#undef STGB

  // epilogue: 32x32 C/D layout: col = lane&31, row = (reg&3)+8*(reg>>2)+4*g
  #pragma unroll
  for (int fn = 0; fn < 2; ++fn) {
    long col = n0 + wc * 64 + fn * 32 + l31;
    float swc = sw[col];
    float bv = bias[col];
    #pragma unroll
    for (int fm = 0; fm < 4; ++fm) {
      long rbase = m0 + wr * 128 + fm * 32 + 4 * g;
      #pragma unroll
      for (int r = 0; r < 16; ++r) {
        long row = rbase + (r & 3) + 8 * (r >> 2);
        out[row * (long)N + col] = (float)acc[fm][fn][r] * sx[row] * swc + bv;
      }
    }
  }
}

extern "C" void kernel_launch(void* const* d_in, const int* in_sizes, int n_in,
                              void* d_out, int out_size, void* d_ws, size_t ws_size,
                              hipStream_t stream) {
  const float* x    = (const float*)d_in[0];
  const float* W    = (const float*)d_in[1];
  const float* b    = (const float*)d_in[2];
  const float* A    = (const float*)d_in[3];
  const float* Bm   = (const float*)d_in[4];

  const long D_out = in_sizes[2];                 // 4096
  const long D_in  = (long)in_sizes[1] / D_out;   // 4096
  const long M     = (long)in_sizes[0] / D_in;    // 16384
  const int  R     = (int)((long)in_sizes[3] / D_in);  // 16
  const int  K = (int)D_in, N = (int)D_out;

  char* wsc = (char*)d_ws;
  signed char*    xq  = (signed char*)wsc;
  unsigned short* wt  = (unsigned short*)(wsc + (size_t)M * K);
  signed char*    wtq = (signed char*)(wsc + (size_t)M * K + (size_t)N * K * 2);
  float* sx = (float*)(wsc + (size_t)M * K + (size_t)N * K * 3);
  float* sw = (float*)(wsc + (size_t)M * K + (size_t)N * K * 3 + (size_t)M * 4);

  quant_x_kernel<<<(int)M, 256, 0, stream>>>(x, xq, sx, K);
  build_wt_kernel<<<(K >> 6) * (N >> 6), 256, 0, stream>>>(W, A, Bm, wt, K, N, R);
  quantize_wt_kernel<<<N, 256, 0, stream>>>(wt, wtq, sw, K);

  int grid = (int)((M / BM) * ((long)N / BN));    // 64 * 16 = 1024
  gemm_kernel<<<grid, 512, 128 * 1024, stream>>>(
      xq, wtq, b, sx, sw, (float*)d_out, (int)M, N, K);
}